// Round 3
// baseline (203.657 us; speedup 1.0000x reference)
//
#include <hip/hip_runtime.h>
#include <stdint.h>

#define IN_FEATURES 65536
#define OUT_FEATURES 262144
#define NUM_CONN 128
#define BLOCK 1024
#define OUT_PER_BLOCK 256                 // 16 outputs per wave, 4 rounds of 4 rows
#define GRID (OUT_FEATURES / OUT_PER_BLOCK)   // 1024 blocks -> 4 per CU: imbalance granularity 25%

__device__ __forceinline__ float bf16_widen(uint16_t h) {
    return __uint_as_float(((uint32_t)h) << 16);
}

// DPP row-rotate move (row = 16 lanes). ctrl: row_ror:N = 0x120 | N.
template <int CTRL>
__device__ __forceinline__ float dpp_mov(float v) {
    int x = __builtin_amdgcn_update_dpp(0, __float_as_int(v), CTRL, 0xF, 0xF, true);
    return __int_as_float(x);
}

__global__ __launch_bounds__(BLOCK, 4)    // 4 waves/EU -> 16 waves/CU, VGPR<=128
void deep_agg_kernel(const float* __restrict__ x,
                     const int* __restrict__ conn,
                     const int* __restrict__ ops,
                     float* __restrict__ out) {
    __shared__ uint16_t xs[IN_FEATURES];   // 128 KiB bf16 copy of x (1 block/CU)
    const int tid = threadIdx.x;

    // ---- Stage x -> LDS as bf16 (RN), coalesced; x is L2-resident ----
    const float4* x4 = (const float4*)x;
    #pragma unroll
    for (int k = 0; k < IN_FEATURES / 4 / BLOCK; ++k) {   // 16 iters
        int i4 = tid + k * BLOCK;
        float4 v = x4[i4];
        uint32_t a = __float_as_uint(v.x), b = __float_as_uint(v.y);
        uint32_t c = __float_as_uint(v.z), d = __float_as_uint(v.w);
        a += 0x7fffu + ((a >> 16) & 1u);
        b += 0x7fffu + ((b >> 16) & 1u);
        c += 0x7fffu + ((c >> 16) & 1u);
        d += 0x7fffu + ((d >> 16) & 1u);
        uint2 p;
        p.x = (a >> 16) | (b & 0xffff0000u);
        p.y = (c >> 16) | (d & 0xffff0000u);
        ((uint2*)xs)[i4] = p;
    }
    __syncthreads();

    // ---- Wave-cooperative: 16 lanes per row, 4 rows per round, 4 rounds ----
    const int lane = tid & 63;
    const int wv   = tid >> 6;
    const int j    = lane & 15;    // position within 16-lane row group
    const int g    = lane >> 4;    // which of 4 rows this round
    const int o_wave = blockIdx.x * OUT_PER_BLOCK + wv * 16;

    // Row for group g in round r: o_wave + 4*r + g. Row stride = 128 ints = 32 int4.
    const int4* base = (const int4*)(conn + (size_t)(o_wave + g) * NUM_CONN);

    int4 v0 = base[j];          // bytes [j*16, j*16+16)   of row
    int4 v1 = base[j + 16];     // bytes [256+j*16, ...)   of row
    float res_mn = 0.f, res_mx = 0.f;

    #pragma unroll
    for (int r = 0; r < 4; ++r) {
        int4 n0, n1;
        if (r < 3) {            // prefetch next round's indices (4 rows ahead = 128 int4)
            n0 = base[(r + 1) * 128 + j];
            n1 = base[(r + 1) * 128 + j + 16];
        }

        float f0 = bf16_widen(xs[v0.x]), f1 = bf16_widen(xs[v0.y]);
        float f2 = bf16_widen(xs[v0.z]), f3 = bf16_widen(xs[v0.w]);
        float f4 = bf16_widen(xs[v1.x]), f5 = bf16_widen(xs[v1.y]);
        float f6 = bf16_widen(xs[v1.z]), f7 = bf16_widen(xs[v1.w]);

        float mn = fminf(fminf(fminf(f0, f1), fminf(f2, f3)),
                         fminf(fminf(f4, f5), fminf(f6, f7)));
        float mx = fmaxf(fmaxf(fmaxf(f0, f1), fmaxf(f2, f3)),
                         fmaxf(fmaxf(f4, f5), fmaxf(f6, f7)));

        // 16-lane reduction, pure VALU (DPP row rotates; LDS pipe stays free)
        mn = fminf(mn, dpp_mov<0x121>(mn));  mx = fmaxf(mx, dpp_mov<0x121>(mx));
        mn = fminf(mn, dpp_mov<0x122>(mn));  mx = fmaxf(mx, dpp_mov<0x122>(mx));
        mn = fminf(mn, dpp_mov<0x124>(mn));  mx = fmaxf(mx, dpp_mov<0x124>(mx));
        mn = fminf(mn, dpp_mov<0x128>(mn));  mx = fmaxf(mx, dpp_mov<0x128>(mx));

        // lane j == r keeps round r's result for its group-row
        bool keep = (j == r);
        res_mn = keep ? mn : res_mn;
        res_mx = keep ? mx : res_mx;

        v0 = n0; v1 = n1;
    }

    // lane (g, j<4) holds output o_wave + 4*j + g; 16 stores/wave, one 64 B line
    if (j < 4) {
        const int oidx = o_wave + 4 * j + g;
        out[oidx] = (ops[oidx] == 0) ? res_mn : res_mx;
    }
}

extern "C" void kernel_launch(void* const* d_in, const int* in_sizes, int n_in,
                              void* d_out, int out_size, void* d_ws, size_t ws_size,
                              hipStream_t stream) {
    const float* x    = (const float*)d_in[0];
    const int*   conn = (const int*)d_in[1];
    const int*   ops  = (const int*)d_in[2];
    float*       out  = (float*)d_out;
    deep_agg_kernel<<<GRID, BLOCK, 0, stream>>>(x, conn, ops, out);
}

// Round 5
// 189.102 us; speedup vs baseline: 1.0770x; 1.0770x over previous
//
#include <hip/hip_runtime.h>
#include <stdint.h>

#define IN_FEATURES 65536
#define OUT_FEATURES 262144
#define NUM_CONN 128
#define BLOCK 1024
#define WAVES (BLOCK / 64)          // 16 waves
#define OUT_PER_WAVE 64
#define GRID (OUT_FEATURES / (WAVES * OUT_PER_WAVE))   // 256 blocks, 1/CU (128 KiB LDS)

typedef int v4i __attribute__((ext_vector_type(4)));   // native vector: nontemporal-load OK

__device__ __forceinline__ float bf16_widen(uint16_t h) {
    return __uint_as_float(((uint32_t)h) << 16);
}

// DPP row-rotate move (row = 16 lanes). ctrl: row_ror:N = 0x120 | N.
template <int CTRL>
__device__ __forceinline__ float dpp_mov(float v) {
    int x = __builtin_amdgcn_update_dpp(0, __float_as_int(v), CTRL, 0xF, 0xF, true);
    return __int_as_float(x);
}

__global__ __launch_bounds__(BLOCK, 1)
void deep_agg_kernel(const float* __restrict__ x,
                     const int* __restrict__ conn,
                     const int* __restrict__ ops,
                     float* __restrict__ out) {
    __shared__ uint16_t xs[IN_FEATURES];   // 128 KiB bf16 copy of x
    const int tid = threadIdx.x;

    // ---- Stage x -> LDS as bf16 (RN), coalesced ----
    const float4* x4 = (const float4*)x;
    #pragma unroll
    for (int k = 0; k < IN_FEATURES / 4 / BLOCK; ++k) {   // 16 iters
        int i4 = tid + k * BLOCK;
        float4 v = x4[i4];
        uint32_t a = __float_as_uint(v.x), b = __float_as_uint(v.y);
        uint32_t c = __float_as_uint(v.z), d = __float_as_uint(v.w);
        a += 0x7fffu + ((a >> 16) & 1u);
        b += 0x7fffu + ((b >> 16) & 1u);
        c += 0x7fffu + ((c >> 16) & 1u);
        d += 0x7fffu + ((d >> 16) & 1u);
        uint2 p;
        p.x = (a >> 16) | (b & 0xffff0000u);
        p.y = (c >> 16) | (d & 0xffff0000u);
        ((uint2*)xs)[i4] = p;
    }
    __syncthreads();

    // ---- Wave-cooperative: 16 lanes per row, 4 rows per round, 16 rounds ----
    const int lane = tid & 63;
    const int wv   = tid >> 6;
    const int j    = lane & 15;    // position within 16-lane row group
    const int g    = lane >> 4;    // which of 4 rows this round
    const int o_base = (blockIdx.x * WAVES + wv) * OUT_PER_WAVE;

    // Row for group g in round r: o_base + 4*r + g. Round stride = 4 rows = 128 int4.
    const v4i* base = (const v4i*)(conn + (size_t)(o_base + g) * NUM_CONN);

    // 2-round-deep software pipeline: 4 x int4 (64 B/lane) in flight.
    // conn is consumed exactly once -> nontemporal to bypass cache pollution.
    v4i a0 = __builtin_nontemporal_load(&base[j]);
    v4i a1 = __builtin_nontemporal_load(&base[j + 16]);
    v4i b0 = __builtin_nontemporal_load(&base[128 + j]);
    v4i b1 = __builtin_nontemporal_load(&base[128 + j + 16]);

    float res_mn = 0.f, res_mx = 0.f;
    #pragma unroll
    for (int r = 0; r < 16; ++r) {
        v4i c0, c1;
        if (r < 14) {   // prefetch round r+2 while rounds r (here) and r+1 (in regs) proceed
            c0 = __builtin_nontemporal_load(&base[(r + 2) * 128 + j]);
            c1 = __builtin_nontemporal_load(&base[(r + 2) * 128 + j + 16]);
        }

        float f0 = bf16_widen(xs[a0.x]), f1 = bf16_widen(xs[a0.y]);
        float f2 = bf16_widen(xs[a0.z]), f3 = bf16_widen(xs[a0.w]);
        float f4 = bf16_widen(xs[a1.x]), f5 = bf16_widen(xs[a1.y]);
        float f6 = bf16_widen(xs[a1.z]), f7 = bf16_widen(xs[a1.w]);

        float mn = fminf(fminf(fminf(f0, f1), fminf(f2, f3)),
                         fminf(fminf(f4, f5), fminf(f6, f7)));
        float mx = fmaxf(fmaxf(fmaxf(f0, f1), fmaxf(f2, f3)),
                         fmaxf(fmaxf(f4, f5), fmaxf(f6, f7)));

        // 16-lane reduction, pure VALU (DPP row rotates; LDS pipe stays free)
        mn = fminf(mn, dpp_mov<0x121>(mn));  mx = fmaxf(mx, dpp_mov<0x121>(mx));
        mn = fminf(mn, dpp_mov<0x122>(mn));  mx = fmaxf(mx, dpp_mov<0x122>(mx));
        mn = fminf(mn, dpp_mov<0x124>(mn));  mx = fmaxf(mx, dpp_mov<0x124>(mx));
        mn = fminf(mn, dpp_mov<0x128>(mn));  mx = fmaxf(mx, dpp_mov<0x128>(mx));

        // lane j == r keeps round r's result for its group-row
        bool keep = (j == r);
        res_mn = keep ? mn : res_mn;
        res_mx = keep ? mx : res_mx;

        a0 = b0; a1 = b1; b0 = c0; b1 = c1;   // rotate pipeline
    }

    // lane l holds output o_base + 4*(l&15) + (l>>4): dense permuted 256 B region
    const int oidx = o_base + 4 * j + g;
    out[oidx] = (ops[oidx] == 0) ? res_mn : res_mx;
}

extern "C" void kernel_launch(void* const* d_in, const int* in_sizes, int n_in,
                              void* d_out, int out_size, void* d_ws, size_t ws_size,
                              hipStream_t stream) {
    const float* x    = (const float*)d_in[0];
    const int*   conn = (const int*)d_in[1];
    const int*   ops  = (const int*)d_in[2];
    float*       out  = (float*)d_out;
    deep_agg_kernel<<<GRID, BLOCK, 0, stream>>>(x, conn, ops, out);
}